// Round 6
// baseline (118.579 us; speedup 1.0000x reference)
//
#include <hip/hip_runtime.h>

#define V_IN 40962
#define V_OUT 163842
#define NCH 64
#define CTOT 256
#define NSLICE 8           // channel slices == XCD count

typedef float    f2 __attribute__((ext_vector_type(2)));
typedef float    f4 __attribute__((ext_vector_type(4)));
typedef _Float16 h4 __attribute__((ext_vector_type(4)));

// ---------------- transpose+downcast: x[2][256][V_IN] f32 -> xT[2][V_IN][256] fp16 ----------------
__global__ __launch_bounds__(256) void transpose_k(const float* __restrict__ x,
                                                   _Float16* __restrict__ xT) {
    __shared__ float tile[64][65];   // [v][c]
    const int b  = blockIdx.z;
    const int v0 = blockIdx.x * 64;
    const int c0 = blockIdx.y * 64;
    const int t  = threadIdx.x;
    const int i  = t & 15;
    const int s  = t >> 4;           // 0..15
#pragma unroll
    for (int p = 0; p < 4; ++p) {
        int c = s + 16 * p;
        int v = 4 * i;
        f4 val = {0.f, 0.f, 0.f, 0.f};
        const float* src = x + ((size_t)b * CTOT + c0 + c) * V_IN + v0 + v;
        if (v0 + v + 3 < V_IN) {
            val = __builtin_nontemporal_load((const f4*)src);
        } else {
            if (v0 + v     < V_IN) val.x = src[0];
            if (v0 + v + 1 < V_IN) val.y = src[1];
            if (v0 + v + 2 < V_IN) val.z = src[2];
            if (v0 + v + 3 < V_IN) val.w = src[3];
        }
        tile[v    ][c] = val.x;
        tile[v + 1][c] = val.y;
        tile[v + 2][c] = val.z;
        tile[v + 3][c] = val.w;
    }
    __syncthreads();
#pragma unroll
    for (int p = 0; p < 4; ++p) {
        int v = s + 16 * p;
        if (v0 + v < V_IN) {
            h4 val;
            val.x = (_Float16)tile[v][4 * i];
            val.y = (_Float16)tile[v][4 * i + 1];
            val.z = (_Float16)tile[v][4 * i + 2];
            val.w = (_Float16)tile[v][4 * i + 3];
            *(h4*)(xT + ((size_t)b * V_IN + v0 + v) * CTOT + c0 + 4 * i) = val;
        }
    }
}

// ---------------- per-output attention math (f32 internal) ----------------
__device__ __forceinline__ float attn_one(const float vals[8], const f2 (&cs2)[8][4]) {
    f2 s2[4];
#pragma unroll
    for (int j = 0; j < 4; ++j) s2[j] = cs2[0][j] * vals[0];
#pragma unroll
    for (int k = 1; k < 8; ++k) {
        f2 vk = {vals[k], vals[k]};
#pragma unroll
        for (int j = 0; j < 4; ++j)
            s2[j] = __builtin_elementwise_fma(vk, cs2[k][j], s2[j]);
    }
    f2 m01 = __builtin_elementwise_max(s2[0], s2[1]);
    f2 m23 = __builtin_elementwise_max(s2[2], s2[3]);
    f2 mm  = __builtin_elementwise_max(m01, m23);
    float m = fmaxf(mm.x, mm.y);
    const float C = 0.18033688011112042f;   // log2(e)/8
    float nmC = m * (-C);
    f2 C2   = {C, C};
    f2 nmC2 = {nmC, nmC};
    f2 sum2 = {0.f, 0.f}, num2 = {0.f, 0.f};
#pragma unroll
    for (int j = 0; j < 4; ++j) {
        f2 tt = __builtin_elementwise_fma(s2[j], C2, nmC2);   // s*C - m*C
        f2 e;
        e.x = __builtin_amdgcn_exp2f(tt.x);
        e.y = __builtin_amdgcn_exp2f(tt.y);
        sum2 += e;
        f2 v2 = {vals[2 * j], vals[2 * j + 1]};
        num2 = __builtin_elementwise_fma(v2, e, num2);
    }
    float sum = sum2.x + sum2.y;
    float num = num2.x + num2.y;
    return num * __builtin_amdgcn_rcpf(sum);
}

__device__ __forceinline__ void unpack2(const h4& a0, const h4& a1, float (&vals)[8]) {
    vals[0] = (float)a0.x; vals[1] = (float)a1.x;
    vals[2] = (float)a0.y; vals[3] = (float)a1.y;
    vals[4] = (float)a0.z; vals[5] = (float)a1.z;
    vals[6] = (float)a0.w; vals[7] = (float)a1.w;
}

// ---------------- fused gather + attn + softmax + weighted sum ----------------
// Block = one 64-v tile x one channel-slice (8 cgroups) x both b  -> 1024 outputs.
// slice = blockIdx.x & 7 pins each slice to one XCD (default round-robin dispatch),
// so each XCD's L2 only sees its 5.25 MB slice of xT.
template <int DIRECT>
__global__ __launch_bounds__(256) void fused_k(const _Float16* __restrict__ xsrc16,
                                               const float* __restrict__ xsrc32,
                                               const float* __restrict__ coeffs,
                                               const int* __restrict__ map,
                                               float* __restrict__ out) {
    __shared__ _Float16 otile[16][68];   // row = b*8+cgl, col = v-local (pad 68 for h4 align)
    __shared__ int      jmap[128];

    const int tid   = threadIdx.x;
    const int bid   = blockIdx.x;
    const int slice = bid & (NSLICE - 1);
    const int tile  = bid >> 3;
    const int vbase = tile * 64;
    const bool full = (vbase + 64 <= V_OUT);

    if (tid < 128) {
        int gi = vbase * 2 + tid;
        jmap[tid] = (gi < 2 * V_OUT) ? map[gi] : 0;
    }

    // wave-uniform coeff loads -> s_load (SGPRs)
    f2 cs2[8][4];
#pragma unroll
    for (int k = 0; k < 8; ++k)
#pragma unroll
        for (int j = 0; j < 4; ++j)
            cs2[k][j] = *(const f2*)(coeffs + k * 8 + 2 * j);

    __syncthreads();

    const int lane = tid & 63;
    const int w    = tid >> 6;
    const int b    = w >> 1;        // batch of this wave
    const int par  = w & 1;         // v-octet parity
    const int vs   = lane >> 3;     // v slot 0..7
    const int cgl  = lane & 7;      // channel-group within slice (consecutive lanes -> 64B line)

    const _Float16* xb = xsrc16 + (size_t)b * V_IN * CTOT + (slice * 8 + cgl) * 4;

    h4 A0[4], A1[4];
    if (!DIRECT) {
        // issue all 8 gathers (4 octets x 2 verts), then compute — static reg indexing
#pragma unroll
        for (int q = 0; q < 4; ++q) {
            int vl = (par + 2 * q) * 8 + vs;
            int2 jj = *(const int2*)&jmap[2 * vl];
            A0[q] = *(const h4*)(xb + (size_t)jj.x * CTOT);
            A1[q] = *(const h4*)(xb + (size_t)jj.y * CTOT);
        }
    } else {
#pragma unroll
        for (int q = 0; q < 4; ++q) {
            int vl = (par + 2 * q) * 8 + vs;
            int2 jj = *(const int2*)&jmap[2 * vl];
#pragma unroll
            for (int e = 0; e < 4; ++e) {
                A0[q][e] = (_Float16)xsrc32[((size_t)b * CTOT + (slice * 8 + cgl) * 4 + e) * V_IN + jj.x];
                A1[q][e] = (_Float16)xsrc32[((size_t)b * CTOT + (slice * 8 + cgl) * 4 + e) * V_IN + jj.y];
            }
        }
    }
#pragma unroll
    for (int q = 0; q < 4; ++q) {
        int vl = (par + 2 * q) * 8 + vs;
        float vals[8];
        unpack2(A0[q], A1[q], vals);
        otile[b * 8 + cgl][vl] = (_Float16)attn_one(vals, cs2);
    }

    __syncthreads();

    // write-out: 256 lanes = 16 rows x 16 v-chunks of 4; 256B contiguous per row-chunk set
    const int r  = tid >> 4;            // 0..15  (b = r>>3, cgl = r&7)
    const int vc = tid & 15;            // v-chunk
    const int bb = r >> 3;
    const int cc = slice * 8 + (r & 7);
    h4 hv = *(const h4*)&otile[r][vc * 4];
    float* op = out + ((size_t)bb * NCH + cc) * V_OUT + vbase + vc * 4;
    if (full) {
        f4 val = {(float)hv.x, (float)hv.y, (float)hv.z, (float)hv.w};
        __builtin_nontemporal_store(val, (f4*)op);
    } else {
#pragma unroll
        for (int e = 0; e < 4; ++e) {
            int v = vbase + vc * 4 + e;
            if (v < V_OUT) op[e] = (float)hv[e];
        }
    }
}

extern "C" void kernel_launch(void* const* d_in, const int* in_sizes, int n_in,
                              void* d_out, int out_size, void* d_ws, size_t ws_size,
                              hipStream_t stream) {
    const float* x      = (const float*)d_in[0];
    const float* coeffs = (const float*)d_in[1];
    const int*   map    = (const int*)d_in[2];
    float*       out    = (float*)d_out;

    const size_t xT_bytes = (size_t)2 * V_IN * CTOT * sizeof(_Float16);
    const int ntiles  = (V_OUT + 63) / 64;
    const int nblocks = ntiles * NSLICE;

    if (ws_size >= xT_bytes) {
        _Float16* xT = (_Float16*)d_ws;
        dim3 tgrid((V_IN + 63) / 64, CTOT / 64, 2);
        transpose_k<<<tgrid, dim3(256), 0, stream>>>(x, xT);
        fused_k<0><<<nblocks, 256, 0, stream>>>(xT, nullptr, coeffs, map, out);
    } else {
        fused_k<1><<<nblocks, 256, 0, stream>>>(nullptr, x, coeffs, map, out);
    }
}